// Round 11
// baseline (35.805 us; speedup 1.0000x reference)
//
#include <hip/hip_runtime.h>
#include <hip/hip_bf16.h>

// ---------------------------------------------------------------------------
// QuantumNeuralNetwork: out[b][q] = <psi_b| U^dag Z_q U |psi_b>.
// Kernel 1: build W = [Re(U); Im(U)] (128x128 bf16 x2) in d_ws, stored in
//           mfma_f32_16x16x32_bf16 A-fragment order.
// Kernel 2: 512-thread blocks, 2/CU. One barrier total (after W->LDS bcast);
//           afterwards each wave runs FREE: 32 own rows loaded straight from
//           global into B-frags, W A-frags read from LDS per state-group,
//           Walsh z-accumulation fully in registers, shfl reduce, write.
//           Decoupled waves keep continuous HBM pressure (r5-r10 showed
//           barrier-coupled phases cap effective BW at ~57%).
// ---------------------------------------------------------------------------

typedef __attribute__((ext_vector_type(8))) short short8;   // 8 x bf16
typedef __attribute__((ext_vector_type(4))) float f32x4;    // 16x16 acc

static __device__ __forceinline__ short f2bf(float f) {
  __bf16 h = (__bf16)f;
  return __builtin_bit_cast(short, h);
}

static __device__ __forceinline__ void gl16(const void* g, void* l) {
  __builtin_amdgcn_global_load_lds(
      (const __attribute__((address_space(1))) void*)g,
      (__attribute__((address_space(3))) void*)l, 16, 0, 0);
}

// 16x16x32 A-fragment order. frag(P, g=s>>4, kf=k>>5);
// lane = (s&15) + 16*((k>>3)&3); elem = k&7.  Flat short index:
static __device__ __forceinline__ int widx16(int P, int s, int k) {
  return (((P * 8 + (s >> 4)) * 4 + (k >> 5)) * 64 +
          ((s & 15) + 16 * ((k >> 3) & 3))) * 8 + (k & 7);
}

// ------------------------------- kernel 1 ----------------------------------
// 128 blocks (one column k each) x 64 threads. Lane l holds states 2l, 2l+1.
__global__ void qnn_build_w(const float* __restrict__ wts,
                            short* __restrict__ W) {
  const int k = blockIdx.x;
  const int l = threadIdx.x;

  float c0r = (2 * l     == k) ? 1.f : 0.f, c0i = 0.f;
  float c1r = (2 * l + 1 == k) ? 1.f : 0.f, c1i = 0.f;

  for (int layer = 0; layer < 2; ++layer) {
    for (int q = 0; q < 7; ++q) {
      const float t0 = 0.5f * wts[(layer * 7 + q) * 3 + 0];
      const float t1 = 0.5f * wts[(layer * 7 + q) * 3 + 1];
      const float t2 = 0.5f * wts[(layer * 7 + q) * 3 + 2];
      const float cx = __cosf(t0), sx = __sinf(t0);
      const float cy = __cosf(t1), sy = __sinf(t1);
      const float cz = __cosf(t2), sz = __sinf(t2);
      const float m00r =  cy * cx, m00i =  sy * sx;
      const float m01r = -sy * cx, m01i = -cy * sx;
      const float m10r =  sy * cx, m10i = -cy * sx;
      const float m11r =  cy * cx, m11i = -sy * sx;
      const float g00r = m00r * cz + m00i * sz, g00i = m00i * cz - m00r * sz;
      const float g01r = m01r * cz + m01i * sz, g01i = m01i * cz - m01r * sz;
      const float g10r = m10r * cz - m10i * sz, g10i = m10i * cz + m10r * sz;
      const float g11r = m11r * cz - m11i * sz, g11i = m11i * cz + m11r * sz;

      const int b = 6 - q;
      if (b == 0) {
        const float n0r = g00r*c0r - g00i*c0i + g01r*c1r - g01i*c1i;
        const float n0i = g00r*c0i + g00i*c0r + g01r*c1i + g01i*c1r;
        const float n1r = g10r*c0r - g10i*c0i + g11r*c1r - g11i*c1i;
        const float n1i = g10r*c0i + g10i*c0r + g11r*c1i + g11i*c1r;
        c0r = n0r; c0i = n0i; c1r = n1r; c1i = n1i;
      } else {
        const int xm  = 1 << (b - 1);
        const int myb = (l >> (b - 1)) & 1;
        const float p0r = __shfl_xor(c0r, xm), p0i = __shfl_xor(c0i, xm);
        const float p1r = __shfl_xor(c1r, xm), p1i = __shfl_xor(c1i, xm);
        const float gar = myb ? g11r : g00r, gai = myb ? g11i : g00i;
        const float gbr = myb ? g10r : g01r, gbi = myb ? g10i : g01i;
        const float n0r = gar*c0r - gai*c0i + gbr*p0r - gbi*p0i;
        const float n0i = gar*c0i + gai*c0r + gbr*p0i + gbi*p0r;
        const float n1r = gar*c1r - gai*c1i + gbr*p1r - gbi*p1i;
        const float n1i = gar*c1i + gai*c1r + gbr*p1i + gbi*p1r;
        c0r = n0r; c0i = n0i; c1r = n1r; c1i = n1i;
      }
    }
    #pragma unroll
    for (int q = 0; q < 7; ++q) {
      const int bc = 6 - q;
      const int bt = 6 - ((q + 1) % 7);
      if (bt == 0) {
        if (l & 1) { float tr=c0r, ti=c0i; c0r=c1r; c0i=c1i; c1r=tr; c1i=ti; }
      } else if (bc == 0) {
        c1r = __shfl_xor(c1r, 32);
        c1i = __shfl_xor(c1i, 32);
      } else {
        const int xm = 1 << (bt - 1);
        const float p0r = __shfl_xor(c0r, xm), p0i = __shfl_xor(c0i, xm);
        const float p1r = __shfl_xor(c1r, xm), p1i = __shfl_xor(c1i, xm);
        if ((l >> (bc - 1)) & 1) { c0r=p0r; c0i=p0i; c1r=p1r; c1i=p1i; }
      }
    }
  }

  W[widx16(0, 2 * l,     k)] = f2bf(c0r);
  W[widx16(0, 2 * l + 1, k)] = f2bf(c1r);
  W[widx16(1, 2 * l,     k)] = f2bf(c0i);
  W[widx16(1, 2 * l + 1, k)] = f2bf(c1i);
}

// ------------------------------- kernel 2 ----------------------------------
// 512 threads (8 waves), 2 blocks/CU. Wave handles 32 rows alone (2 sets of
// 16). B-frag lane l: row = (l&15), k = (l>>4)*8+e within kf*32 window ->
// direct global float4 loads, 128-B-line coalesced across 16 rows.
// A-frags (all 128 states, both planes) = LDS, fragment-order, lane-linear
// ds_read_b128, shared across the 2 row-sets.
__global__ __launch_bounds__(512, 4) void qnn_main(
    const float* __restrict__ x, const short* __restrict__ W,
    float* __restrict__ out, int nrows) {
  const int tid = threadIdx.x;
  const int l   = tid & 63;
  const int wv  = tid >> 6;          // 0..7
  const int q4  = l >> 4;            // 0..3 (k-quarter / D state-quarter)
  const int r16 = l & 15;            // row-within-set / D col

  __shared__ short Wl[32768];        // 64 KiB: full W in A-frag order

  // ---- W -> LDS broadcast (linear both sides; r6/r8-verified gl16 pattern)
  {
    const char* gw = (const char*)W;
    char* lw = (char*)Wl;
    #pragma unroll
    for (int i = 0; i < 8; ++i) {
      const int off = wv * 8192 + i * 1024 + l * 16;
      gl16(gw + off, lw + off);
    }
  }
  __builtin_amdgcn_sched_barrier(0);

  // ---- x loads: 32 own rows straight to regs (16 dwordx4, issued now)
  const int base  = (blockIdx.x * 8 + wv) * 32;
  const int cbase = (base + 32 <= nrows) ? base : (nrows - 32);  // clamp
  float4 xf[16];
  {
    const char* gx = (const char*)x + (size_t)cbase * 512;
    #pragma unroll
    for (int s = 0; s < 2; ++s)
      #pragma unroll
      for (int kf = 0; kf < 4; ++kf) {
        const int off = (s * 16 + r16) * 512 + kf * 128 + q4 * 32;
        xf[s * 8 + kf * 2]     = *reinterpret_cast<const float4*>(gx + off);
        xf[s * 8 + kf * 2 + 1] = *reinterpret_cast<const float4*>(gx + off + 16);
      }
  }
  __builtin_amdgcn_sched_barrier(0);

  // ---- wait W only (8 oldest vmem ops); 16 x-loads stay in flight
  asm volatile("s_waitcnt vmcnt(16)" ::: "memory");
  __builtin_amdgcn_s_barrier();
  asm volatile("" ::: "memory");
  __builtin_amdgcn_sched_barrier(0);

  // ---- cvt to B-frags (compiler inserts the x drain here)
  short8 bfr0[4], bfr1[4];
  #pragma unroll
  for (int kf = 0; kf < 4; ++kf) {
    const float4 a = xf[kf * 2], b = xf[kf * 2 + 1];
    short8 c;
    c[0]=f2bf(a.x); c[1]=f2bf(a.y); c[2]=f2bf(a.z); c[3]=f2bf(a.w);
    c[4]=f2bf(b.x); c[5]=f2bf(b.y); c[6]=f2bf(b.z); c[7]=f2bf(b.w);
    bfr0[kf] = c;
    const float4 d = xf[8 + kf * 2], e = xf[8 + kf * 2 + 1];
    short8 f;
    f[0]=f2bf(d.x); f[1]=f2bf(d.y); f[2]=f2bf(d.z); f[3]=f2bf(d.w);
    f[4]=f2bf(e.x); f[5]=f2bf(e.y); f[6]=f2bf(e.z); f[7]=f2bf(e.w);
    bfr1[kf] = f;
  }

  // ---- 8 state-groups: 8 ds_read + 16 MFMA each; Walsh accum in regs
  float Tt0 = 0.f, Tt1 = 0.f;
  float U0[7] = {0.f,0.f,0.f,0.f,0.f,0.f,0.f};
  float U1[7] = {0.f,0.f,0.f,0.f,0.f,0.f,0.f};
  const float sg2 = (q4 & 1) ? -1.f : 1.f;   // s-bit2 sign (lane-const)
  const float sg3 = (q4 & 2) ? -1.f : 1.f;   // s-bit3 sign
  const short8* wfrag = reinterpret_cast<const short8*>(Wl);

  #pragma unroll
  for (int g = 0; g < 8; ++g) {
    f32x4 a00 = {0.f,0.f,0.f,0.f};   // plane Re, set 0
    f32x4 a10 = {0.f,0.f,0.f,0.f};   // plane Im, set 0
    f32x4 a01 = {0.f,0.f,0.f,0.f};   // plane Re, set 1
    f32x4 a11 = {0.f,0.f,0.f,0.f};   // plane Im, set 1
    #pragma unroll
    for (int kf = 0; kf < 4; ++kf) {
      const short8 w0 = wfrag[(g * 4 + kf) * 64 + l];          // Re frag
      const short8 w1 = wfrag[((8 + g) * 4 + kf) * 64 + l];    // Im frag
      a00 = __builtin_amdgcn_mfma_f32_16x16x32_bf16(w0, bfr0[kf], a00, 0,0,0);
      a10 = __builtin_amdgcn_mfma_f32_16x16x32_bf16(w1, bfr0[kf], a10, 0,0,0);
      a01 = __builtin_amdgcn_mfma_f32_16x16x32_bf16(w0, bfr1[kf], a01, 0,0,0);
      a11 = __builtin_amdgcn_mfma_f32_16x16x32_bf16(w1, bfr1[kf], a11, 0,0,0);
    }
    // s = g*16 + q4*4 + reg;  D: col=r16 (x-row), state-row=q4*4+reg
    {
      const float p0 = a00[0]*a00[0] + a10[0]*a10[0];
      const float p1 = a00[1]*a00[1] + a10[1]*a10[1];
      const float p2 = a00[2]*a00[2] + a10[2]*a10[2];
      const float p3 = a00[3]*a00[3] + a10[3]*a10[3];
      const float s01 = p0 + p1, s23 = p2 + p3;
      const float Tg = s01 + s23;
      U0[0] += (p0 - p1) + (p2 - p3);     // bit0 (reg&1)
      U0[1] += s01 - s23;                 // bit1 (reg>>1)
      U0[2] += sg2 * Tg;                  // bit2 (q4&1)
      U0[3] += sg3 * Tg;                  // bit3 (q4>>1)
      U0[4] += (g & 1) ? -Tg : Tg;        // bit4
      U0[5] += (g & 2) ? -Tg : Tg;        // bit5
      U0[6] += (g & 4) ? -Tg : Tg;        // bit6
      Tt0   += Tg;
    }
    {
      const float p0 = a01[0]*a01[0] + a11[0]*a11[0];
      const float p1 = a01[1]*a01[1] + a11[1]*a11[1];
      const float p2 = a01[2]*a01[2] + a11[2]*a11[2];
      const float p3 = a01[3]*a01[3] + a11[3]*a11[3];
      const float s01 = p0 + p1, s23 = p2 + p3;
      const float Tg = s01 + s23;
      U1[0] += (p0 - p1) + (p2 - p3);
      U1[1] += s01 - s23;
      U1[2] += sg2 * Tg;
      U1[3] += sg3 * Tg;
      U1[4] += (g & 1) ? -Tg : Tg;
      U1[5] += (g & 2) ? -Tg : Tg;
      U1[6] += (g & 4) ? -Tg : Tg;
      Tt1   += Tg;
    }
  }

  // ---- reduce over lane quarters (q4): shfl_xor 16, 32 (broadcasts result)
  float v0[8] = {Tt0, U0[0], U0[1], U0[2], U0[3], U0[4], U0[5], U0[6]};
  float v1[8] = {Tt1, U1[0], U1[1], U1[2], U1[3], U1[4], U1[5], U1[6]};
  #pragma unroll
  for (int i = 0; i < 8; ++i) {
    v0[i] += __shfl_xor(v0[i], 16);
    v0[i] += __shfl_xor(v0[i], 32);
    v1[i] += __shfl_xor(v1[i], 16);
    v1[i] += __shfl_xor(v1[i], 32);
  }

  // ---- write: z_q = U_{6-q} / T ; lanes 0-15 set0 rows, 16-31 set1 rows
  if (base < nrows) {
    if (l < 16) {
      const float inv = 1.0f / v0[0];
      float* o = out + (size_t)(base + l) * 7;
      o[0] = v0[7] * inv;  // bit6 (wire 0 = MSB)
      o[1] = v0[6] * inv;
      o[2] = v0[5] * inv;
      o[3] = v0[4] * inv;
      o[4] = v0[3] * inv;
      o[5] = v0[2] * inv;
      o[6] = v0[1] * inv;
    } else if (l < 32) {
      const float inv = 1.0f / v1[0];
      float* o = out + (size_t)(base + 16 + (l & 15)) * 7;
      o[0] = v1[7] * inv;
      o[1] = v1[6] * inv;
      o[2] = v1[5] * inv;
      o[3] = v1[4] * inv;
      o[4] = v1[3] * inv;
      o[5] = v1[2] * inv;
      o[6] = v1[1] * inv;
    }
  }
}

// ------------------------------- launcher ----------------------------------
extern "C" void kernel_launch(void* const* d_in, const int* in_sizes, int n_in,
                              void* d_out, int out_size, void* d_ws, size_t ws_size,
                              hipStream_t stream) {
  const float* x   = (const float*)d_in[0];
  const float* wts = (const float*)d_in[1];
  float* out = (float*)d_out;
  short* W   = (short*)d_ws;               // 2 * 128*128 bf16 = 64 KiB

  const int B    = in_sizes[0] / 128;      // rows
  const int grid = (B + 255) / 256;        // 256 rows per 512-thread block

  qnn_build_w<<<128, 64, 0, stream>>>(wts, W);
  qnn_main<<<grid, 512, 0, stream>>>(x, W, out, B);
}

// Round 12
// 29.782 us; speedup vs baseline: 1.2023x; 1.2023x over previous
//
#include <hip/hip_runtime.h>
#include <hip/hip_bf16.h>

// ---------------------------------------------------------------------------
// QuantumNeuralNetwork: out[b][q] = <psi_b| U^dag Z_q U |psi_b>.
// Kernel 1: build W = [Re(U); Im(U)] (128x128 bf16 x2) in d_ws, stored in
//           mfma_f32_32x32x16_bf16 A-fragment order (r4-r9 verified).
// Kernel 2: persistent grid-stride, grid=1024 (4 blocks/CU), 4 tiles of
//           32 rows per block. A-preload once per block (amortized 128 rows,
//           2x r5). Double-buffered xb/red, ONE barrier per tile; loads for
//           tile t+2 in flight across it (wait covered by COMPUTE(t)).
// ---------------------------------------------------------------------------

typedef __attribute__((ext_vector_type(8)))  short short8;   // 8 x bf16
typedef __attribute__((ext_vector_type(16))) float f32x16;   // 32x32 acc

static __device__ __forceinline__ short f2bf(float f) {
  __bf16 h = (__bf16)f;
  return __builtin_bit_cast(short, h);
}

// 32x32x16 A-fragment order: frag(P, wv=s>>5, j=k>>4);
// lane = (s&31) + 32*((k>>3)&1); elem = k&7.  Flat short index:
static __device__ __forceinline__ int widx(int P, int s, int k) {
  return ((((P << 2) + (s >> 5)) * 8 + (k >> 4)) * 64 +
          ((s & 31) + ((k >> 3) & 1) * 32)) * 8 + (k & 7);
}

// ------------------------------- kernel 1 ----------------------------------
// 128 blocks (one column k each) x 64 threads. Lane l holds states 2l, 2l+1.
__global__ void qnn_build_w(const float* __restrict__ wts,
                            short* __restrict__ W) {
  const int k = blockIdx.x;
  const int l = threadIdx.x;

  float c0r = (2 * l     == k) ? 1.f : 0.f, c0i = 0.f;
  float c1r = (2 * l + 1 == k) ? 1.f : 0.f, c1i = 0.f;

  for (int layer = 0; layer < 2; ++layer) {
    for (int q = 0; q < 7; ++q) {
      const float t0 = 0.5f * wts[(layer * 7 + q) * 3 + 0];
      const float t1 = 0.5f * wts[(layer * 7 + q) * 3 + 1];
      const float t2 = 0.5f * wts[(layer * 7 + q) * 3 + 2];
      const float cx = __cosf(t0), sx = __sinf(t0);
      const float cy = __cosf(t1), sy = __sinf(t1);
      const float cz = __cosf(t2), sz = __sinf(t2);
      const float m00r =  cy * cx, m00i =  sy * sx;
      const float m01r = -sy * cx, m01i = -cy * sx;
      const float m10r =  sy * cx, m10i = -cy * sx;
      const float m11r =  cy * cx, m11i = -sy * sx;
      const float g00r = m00r * cz + m00i * sz, g00i = m00i * cz - m00r * sz;
      const float g01r = m01r * cz + m01i * sz, g01i = m01i * cz - m01r * sz;
      const float g10r = m10r * cz - m10i * sz, g10i = m10i * cz + m10r * sz;
      const float g11r = m11r * cz - m11i * sz, g11i = m11i * cz + m11r * sz;

      const int b = 6 - q;
      if (b == 0) {
        const float n0r = g00r*c0r - g00i*c0i + g01r*c1r - g01i*c1i;
        const float n0i = g00r*c0i + g00i*c0r + g01r*c1i + g01i*c1r;
        const float n1r = g10r*c0r - g10i*c0i + g11r*c1r - g11i*c1i;
        const float n1i = g10r*c0i + g10i*c0r + g11r*c1i + g11i*c1r;
        c0r = n0r; c0i = n0i; c1r = n1r; c1i = n1i;
      } else {
        const int xm  = 1 << (b - 1);
        const int myb = (l >> (b - 1)) & 1;
        const float p0r = __shfl_xor(c0r, xm), p0i = __shfl_xor(c0i, xm);
        const float p1r = __shfl_xor(c1r, xm), p1i = __shfl_xor(c1i, xm);
        const float gar = myb ? g11r : g00r, gai = myb ? g11i : g00i;
        const float gbr = myb ? g10r : g01r, gbi = myb ? g10i : g01i;
        const float n0r = gar*c0r - gai*c0i + gbr*p0r - gbi*p0i;
        const float n0i = gar*c0i + gai*c0r + gbr*p0i + gbi*p0r;
        const float n1r = gar*c1r - gai*c1i + gbr*p1r - gbi*p1i;
        const float n1i = gar*c1i + gai*c1r + gbr*p1i + gbi*p1r;
        c0r = n0r; c0i = n0i; c1r = n1r; c1i = n1i;
      }
    }
    #pragma unroll
    for (int q = 0; q < 7; ++q) {
      const int bc = 6 - q;
      const int bt = 6 - ((q + 1) % 7);
      if (bt == 0) {
        if (l & 1) { float tr=c0r, ti=c0i; c0r=c1r; c0i=c1i; c1r=tr; c1i=ti; }
      } else if (bc == 0) {
        c1r = __shfl_xor(c1r, 32);
        c1i = __shfl_xor(c1i, 32);
      } else {
        const int xm = 1 << (bt - 1);
        const float p0r = __shfl_xor(c0r, xm), p0i = __shfl_xor(c0i, xm);
        const float p1r = __shfl_xor(c1r, xm), p1i = __shfl_xor(c1i, xm);
        if ((l >> (bc - 1)) & 1) { c0r=p0r; c0i=p0i; c1r=p1r; c1i=p1i; }
      }
    }
  }

  W[widx(0, 2 * l,     k)] = f2bf(c0r);
  W[widx(0, 2 * l + 1, k)] = f2bf(c1r);
  W[widx(1, 2 * l,     k)] = f2bf(c0i);
  W[widx(1, 2 * l + 1, k)] = f2bf(c1i);
}

// ------------------------------- kernel 2 ----------------------------------
// 256 threads (4 waves), persistent: tiles t, t+stride, ... (4 each).
// Wave wv owns states [32wv,32wv+32) (A-frags, 64 VGPRs, coalesced preload).
// x loads: p=i*256+tid, r=p>>4, q=p&15 -> contiguous aligned 1 KiB per wave
// instruction (verified best coalescing, r1-r5).
__global__ __launch_bounds__(256, 4) void qnn_main(
    const float* __restrict__ x, const short* __restrict__ W,
    float* __restrict__ out, int ntiles, int stride) {
  const int tid = threadIdx.x;
  const int l   = tid & 63;
  const int wv  = tid >> 6;
  const int col = l & 31;
  const int h   = l >> 5;

  __shared__ short8 xb[2][512];       // 2 x (32 rows x 16 chunks), 16 KiB
  __shared__ float  red[2][4][32][6]; // 6 KiB

  // ---- A-preload FIRST (oldest vmcnt; drained by first STAGE wait - L2 hit)
  short8 A0[8], A1[8];
  #pragma unroll
  for (int j = 0; j < 8; ++j) {
    const int off = ((wv * 8 + j) * 64 + l) * 8;
    A0[j] = *reinterpret_cast<const short8*>(W + off);
    A1[j] = *reinterpret_cast<const short8*>(W + 16384 + off);
  }

  float4 fa[2], fb[2];
  const int r = tid >> 4, q = tid & 15;          // fixed row/chunk per thread
  const int sidx = r * 16 + (q ^ (r & 7));       // swizzled LDS slot
  const size_t goff = (size_t)r * 128 + q * 8;   // within-tile global offset

  auto LOAD = [&](int T) {
    const float* gp = x + (size_t)T * 32 * 128 + goff;
    fa[0] = *reinterpret_cast<const float4*>(gp);
    fb[0] = *reinterpret_cast<const float4*>(gp + 4);
    fa[1] = *reinterpret_cast<const float4*>(gp + 2048);   // row r+16
    fb[1] = *reinterpret_cast<const float4*>(gp + 2052);
  };
  auto STAGE = [&](int b) {      // cvt regs -> bf16 swizzled LDS buffer b
    #pragma unroll
    for (int i = 0; i < 2; ++i) {
      short8 c;
      c[0]=f2bf(fa[i].x); c[1]=f2bf(fa[i].y); c[2]=f2bf(fa[i].z); c[3]=f2bf(fa[i].w);
      c[4]=f2bf(fb[i].x); c[5]=f2bf(fb[i].y); c[6]=f2bf(fb[i].z); c[7]=f2bf(fb[i].w);
      xb[b][sidx + i * 256] = c;   // rows r and r+16: same swizzle (r&7 eq)
    }
  };

  auto COMPUTE = [&](int b) {    // 16 ds_read_b128 -> 16 MFMA -> Walsh -> red
    f32x16 acc0 = {0.f,0.f,0.f,0.f,0.f,0.f,0.f,0.f,
                   0.f,0.f,0.f,0.f,0.f,0.f,0.f,0.f};
    f32x16 acc1 = {0.f,0.f,0.f,0.f,0.f,0.f,0.f,0.f,
                   0.f,0.f,0.f,0.f,0.f,0.f,0.f,0.f};
    #pragma unroll
    for (int j = 0; j < 8; ++j) {
      const int qq = j * 2 + h;
      const short8 bfr = xb[b][col * 16 + (qq ^ (col & 7))];
      acc0 = __builtin_amdgcn_mfma_f32_32x32x16_bf16(A0[j], bfr, acc0, 0, 0, 0);
      acc1 = __builtin_amdgcn_mfma_f32_32x32x16_bf16(A1[j], bfr, acc1, 0, 0, 0);
    }
    // Walsh tree over s-bits (verified rounds 0-11)
    float aS[8], aD[8];
    #pragma unroll
    for (int i = 0; i < 8; ++i) {
      const float pe = acc0[2*i]   * acc0[2*i]   + acc1[2*i]   * acc1[2*i];
      const float po = acc0[2*i+1] * acc0[2*i+1] + acc1[2*i+1] * acc1[2*i+1];
      aS[i] = pe + po;
      aD[i] = pe - po;
    }
    float bS[4], bD[4];
    #pragma unroll
    for (int i = 0; i < 4; ++i) {
      bS[i] = aS[2*i] + aS[2*i+1];
      bD[i] = aS[2*i] - aS[2*i+1];
    }
    float u0 = ((aD[0]+aD[1]) + (aD[2]+aD[3])) + ((aD[4]+aD[5]) + (aD[6]+aD[7]));
    float u1 = (bD[0] + bD[1]) + (bD[2] + bD[3]);
    const float cS0 = bS[0] + bS[1], cD0 = bS[0] - bS[1];
    const float cS1 = bS[2] + bS[3], cD1 = bS[2] - bS[3];
    float u3 = cD0 + cD1;
    float u4 = cS0 - cS1;
    float T  = cS0 + cS1;

    const float Tp = __shfl_xor(T, 32);
    const float u2 = h ? (Tp - T) : (T - Tp);
    T += Tp;
    u0 += __shfl_xor(u0, 32);
    u1 += __shfl_xor(u1, 32);
    u3 += __shfl_xor(u3, 32);
    u4 += __shfl_xor(u4, 32);

    if (h == 0) {
      red[b][wv][col][0] = T;
      red[b][wv][col][1] = u0;
      red[b][wv][col][2] = u1;
      red[b][wv][col][3] = u2;
      red[b][wv][col][4] = u3;
      red[b][wv][col][5] = u4;
    }
  };

  auto TAIL = [&](int b, int T) {   // combine waves, 7 outs x 32 rows
    if (tid < 32) {
      const int c = tid;
      const float T0v = red[b][0][c][0], T1v = red[b][1][c][0];
      const float T2v = red[b][2][c][0], T3v = red[b][3][c][0];
      const float sT  = (T0v + T1v) + (T2v + T3v);
      const float inv = 1.0f / sT;     // == 1/||x||^2 (unitarity)
      const float z0 = (T0v + T1v) - (T2v + T3v);
      const float z1 = (T0v - T1v) + (T2v - T3v);
      float zr[5];
      #pragma unroll
      for (int i = 0; i < 5; ++i)
        zr[i] = (red[b][0][c][5-i] + red[b][1][c][5-i]) +
                (red[b][2][c][5-i] + red[b][3][c][5-i]);
      float* o = out + (size_t)(T * 32 + c) * 7;
      o[0] = z0 * inv; o[1] = z1 * inv; o[2] = zr[0] * inv; o[3] = zr[1] * inv;
      o[4] = zr[2] * inv; o[5] = zr[3] * inv; o[6] = zr[4] * inv;
    }
  };

  // ---- prologue: stage tile t0 -> xb[0]; loads for t0+stride in flight
  int t = blockIdx.x;
  LOAD(t);
  STAGE(0);                        // waits t0 (A drains too: L2, cheap)
  if (t + stride < ntiles) LOAD(t + stride);
  asm volatile("s_waitcnt lgkmcnt(0)" ::: "memory");
  __builtin_amdgcn_s_barrier();
  asm volatile("" ::: "memory");

  // ---- main loop: ONE barrier per tile
  int i = 0;
  for (; t < ntiles; t += stride, ++i) {
    const int p = i & 1;
    COMPUTE(p);                    // covers vmcnt latency of tile t+stride
    if (t + stride < ntiles) {
      STAGE(p ^ 1);                // waits t+stride loads (now arrived)
      if (t + 2 * stride < ntiles) LOAD(t + 2 * stride);
    }
    asm volatile("s_waitcnt lgkmcnt(0)" ::: "memory");
    __builtin_amdgcn_s_barrier();  // red[p] ready; xb[p^1] staged
    asm volatile("" ::: "memory");
    TAIL(p, t);                    // overlaps next iteration's COMPUTE
  }
}

// ------------------------------- launcher ----------------------------------
extern "C" void kernel_launch(void* const* d_in, const int* in_sizes, int n_in,
                              void* d_out, int out_size, void* d_ws, size_t ws_size,
                              hipStream_t stream) {
  const float* x   = (const float*)d_in[0];
  const float* wts = (const float*)d_in[1];
  float* out = (float*)d_out;
  short* W   = (short*)d_ws;               // 2 * 128*128 bf16 = 64 KiB

  const int B      = in_sizes[0] / 128;
  const int ntiles = B / 32;               // 32-row tiles (4096)
  const int grid   = ntiles < 1024 ? ntiles : 1024;   // 4 blocks/CU

  qnn_build_w<<<128, 64, 0, stream>>>(wts, W);
  qnn_main<<<grid, 256, 0, stream>>>(x, W, out, ntiles, grid);
}

// Round 13
// 23.897 us; speedup vs baseline: 1.4983x; 1.2463x over previous
//
#include <hip/hip_runtime.h>
#include <hip/hip_bf16.h>

// ---------------------------------------------------------------------------
// QuantumNeuralNetwork: out[b][q] = <psi_b| U^dag Z_q U |psi_b>.
// Kernel 1: build W = [Re(U); Im(U)] as 128x128 bf16 x2 in d_ws, stored in
//           MFMA-A-fragment order (coalesced per-wave preload).
// Kernel 2: ONE 64-row tile per block (grid = B/64 = 2048). Block does:
//           issue x loads -> A preload -> stage bf16 to swizzled LDS ->
//           barrier -> MFMA + Walsh epilogue -> barrier -> tail write.
//           Latency hiding from 4 blocks/CU TLP (16 waves/CU).
// FINAL: best of 13 structural variants (r0-r12); see session journal.
// ---------------------------------------------------------------------------

typedef __attribute__((ext_vector_type(8)))  short short8;   // 8 x bf16
typedef __attribute__((ext_vector_type(16))) float f32x16;   // 32x32 acc

static __device__ __forceinline__ short f2bf(float f) {
  __bf16 h = (__bf16)f;
  return __builtin_bit_cast(short, h);
}

// A-fragment layout: frag(P, wv=s>>5, j=k>>4); lane = (s&31) + 32*((k>>3)&1);
// elem = k&7.  Flat short index:
static __device__ __forceinline__ int widx(int P, int s, int k) {
  return ((((P << 2) + (s >> 5)) * 8 + (k >> 4)) * 64 +
          ((s & 31) + ((k >> 3) & 1) * 32)) * 8 + (k & 7);
}

// ------------------------------- kernel 1 ----------------------------------
// 128 blocks (one column k each) x 64 threads. Lane l holds states 2l, 2l+1.
__global__ void qnn_build_w(const float* __restrict__ wts,
                            short* __restrict__ W) {
  const int k = blockIdx.x;
  const int l = threadIdx.x;

  float c0r = (2 * l     == k) ? 1.f : 0.f, c0i = 0.f;
  float c1r = (2 * l + 1 == k) ? 1.f : 0.f, c1i = 0.f;

  for (int layer = 0; layer < 2; ++layer) {
    for (int q = 0; q < 7; ++q) {
      const float t0 = 0.5f * wts[(layer * 7 + q) * 3 + 0];
      const float t1 = 0.5f * wts[(layer * 7 + q) * 3 + 1];
      const float t2 = 0.5f * wts[(layer * 7 + q) * 3 + 2];
      const float cx = __cosf(t0), sx = __sinf(t0);
      const float cy = __cosf(t1), sy = __sinf(t1);
      const float cz = __cosf(t2), sz = __sinf(t2);
      const float m00r =  cy * cx, m00i =  sy * sx;
      const float m01r = -sy * cx, m01i = -cy * sx;
      const float m10r =  sy * cx, m10i = -cy * sx;
      const float m11r =  cy * cx, m11i = -sy * sx;
      const float g00r = m00r * cz + m00i * sz, g00i = m00i * cz - m00r * sz;
      const float g01r = m01r * cz + m01i * sz, g01i = m01i * cz - m01r * sz;
      const float g10r = m10r * cz - m10i * sz, g10i = m10i * cz + m10r * sz;
      const float g11r = m11r * cz - m11i * sz, g11i = m11i * cz + m11r * sz;

      const int b = 6 - q;
      if (b == 0) {
        const float n0r = g00r*c0r - g00i*c0i + g01r*c1r - g01i*c1i;
        const float n0i = g00r*c0i + g00i*c0r + g01r*c1i + g01i*c1r;
        const float n1r = g10r*c0r - g10i*c0i + g11r*c1r - g11i*c1i;
        const float n1i = g10r*c0i + g10i*c0r + g11r*c1i + g11i*c1r;
        c0r = n0r; c0i = n0i; c1r = n1r; c1i = n1i;
      } else {
        const int xm  = 1 << (b - 1);
        const int myb = (l >> (b - 1)) & 1;
        const float p0r = __shfl_xor(c0r, xm), p0i = __shfl_xor(c0i, xm);
        const float p1r = __shfl_xor(c1r, xm), p1i = __shfl_xor(c1i, xm);
        const float gar = myb ? g11r : g00r, gai = myb ? g11i : g00i;
        const float gbr = myb ? g10r : g01r, gbi = myb ? g10i : g01i;
        const float n0r = gar*c0r - gai*c0i + gbr*p0r - gbi*p0i;
        const float n0i = gar*c0i + gai*c0r + gbr*p0i + gbi*p0r;
        const float n1r = gar*c1r - gai*c1i + gbr*p1r - gbi*p1i;
        const float n1i = gar*c1i + gai*c1r + gbr*p1i + gbi*p1r;
        c0r = n0r; c0i = n0i; c1r = n1r; c1i = n1i;
      }
    }
    #pragma unroll
    for (int q = 0; q < 7; ++q) {
      const int bc = 6 - q;
      const int bt = 6 - ((q + 1) % 7);
      if (bt == 0) {
        if (l & 1) { float tr=c0r, ti=c0i; c0r=c1r; c0i=c1i; c1r=tr; c1i=ti; }
      } else if (bc == 0) {
        c1r = __shfl_xor(c1r, 32);
        c1i = __shfl_xor(c1i, 32);
      } else {
        const int xm = 1 << (bt - 1);
        const float p0r = __shfl_xor(c0r, xm), p0i = __shfl_xor(c0i, xm);
        const float p1r = __shfl_xor(c1r, xm), p1i = __shfl_xor(c1i, xm);
        if ((l >> (bc - 1)) & 1) { c0r=p0r; c0i=p0i; c1r=p1r; c1i=p1i; }
      }
    }
  }

  W[widx(0, 2 * l,     k)] = f2bf(c0r);
  W[widx(0, 2 * l + 1, k)] = f2bf(c1r);
  W[widx(1, 2 * l,     k)] = f2bf(c0i);
  W[widx(1, 2 * l + 1, k)] = f2bf(c1i);
}

// ------------------------------- kernel 2 ----------------------------------
// 256 threads (4 waves), ONE 64-row tile per block. Wave wv owns states
// [32wv,32wv+32) (A-frags, 64 VGPRs, coalesced fragment-order load).
// x loads: p = i*256+tid, row = p>>4, chunk = p&15 -> each wave instruction
// reads a contiguous aligned 1 KiB (best coalescing, verified round 1/2).
__global__ __launch_bounds__(256, 4) void qnn_main(
    const float* __restrict__ x, const short* __restrict__ W,
    float* __restrict__ out) {
  const int tid = threadIdx.x;
  const int l   = tid & 63;
  const int wv  = tid >> 6;
  const int col = l & 31;
  const int h   = l >> 5;

  __shared__ short8 xb[1024];         // 64 rows x 16 chunks (swizzled), 16 KiB
  __shared__ float  red[4][64][7];    // pad 7: conflict-free TAIL reads, 7 KiB

  const int t0 = blockIdx.x;

  // ---- issue x loads first (HBM latency starts now); contiguous mapping
  float4 fa[4], fb[4];
  #pragma unroll
  for (int i = 0; i < 4; ++i) {
    const int p = i * 256 + tid;
    const int r = p >> 4, q = p & 15;
    const float* gp = x + (size_t)(t0 * 64 + r) * 128 + q * 8;
    fa[i] = *reinterpret_cast<const float4*>(gp);
    fb[i] = *reinterpret_cast<const float4*>(gp + 4);
  }

  // ---- A-preload: coalesced fragment-order reads (W is L2-resident)
  short8 A0[8], A1[8];
  #pragma unroll
  for (int j = 0; j < 8; ++j) {
    const int off = ((wv * 8 + j) * 64 + l) * 8;
    A0[j] = *reinterpret_cast<const short8*>(W + off);
    A1[j] = *reinterpret_cast<const short8*>(W + 16384 + off);
  }

  // ---- stage: fp32 regs -> bf16 swizzled LDS
  #pragma unroll
  for (int i = 0; i < 4; ++i) {
    const int p = i * 256 + tid;
    const int r = p >> 4, q = p & 15;
    short8 c;
    c[0]=f2bf(fa[i].x); c[1]=f2bf(fa[i].y); c[2]=f2bf(fa[i].z); c[3]=f2bf(fa[i].w);
    c[4]=f2bf(fb[i].x); c[5]=f2bf(fb[i].y); c[6]=f2bf(fb[i].z); c[7]=f2bf(fb[i].w);
    xb[r * 16 + (q ^ (r & 7))] = c;
  }
  asm volatile("s_waitcnt lgkmcnt(0)" ::: "memory");
  __builtin_amdgcn_s_barrier();
  asm volatile("" ::: "memory");

  // ---- compute: per g-group 16 MFMA + Walsh-tree epilogue
  #pragma unroll
  for (int g = 0; g < 2; ++g) {
    f32x16 acc0 = {0.f,0.f,0.f,0.f,0.f,0.f,0.f,0.f,
                   0.f,0.f,0.f,0.f,0.f,0.f,0.f,0.f};
    f32x16 acc1 = {0.f,0.f,0.f,0.f,0.f,0.f,0.f,0.f,
                   0.f,0.f,0.f,0.f,0.f,0.f,0.f,0.f};
    const int r = g * 32 + col;
    #pragma unroll
    for (int j = 0; j < 8; ++j) {
      const int q = j * 2 + h;
      const short8 bfr = xb[r * 16 + (q ^ (r & 7))];
      acc0 = __builtin_amdgcn_mfma_f32_32x32x16_bf16(A0[j], bfr, acc0, 0, 0, 0);
      acc1 = __builtin_amdgcn_mfma_f32_32x32x16_bf16(A1[j], bfr, acc1, 0, 0, 0);
    }
    // Walsh tree over s-bits (verified rounds 0-12)
    float aS[8], aD[8];
    #pragma unroll
    for (int i = 0; i < 8; ++i) {
      const float pe = acc0[2*i]   * acc0[2*i]   + acc1[2*i]   * acc1[2*i];
      const float po = acc0[2*i+1] * acc0[2*i+1] + acc1[2*i+1] * acc1[2*i+1];
      aS[i] = pe + po;
      aD[i] = pe - po;
    }
    float bS[4], bD[4];
    #pragma unroll
    for (int i = 0; i < 4; ++i) {
      bS[i] = aS[2*i] + aS[2*i+1];
      bD[i] = aS[2*i] - aS[2*i+1];
    }
    float u0 = ((aD[0]+aD[1]) + (aD[2]+aD[3])) + ((aD[4]+aD[5]) + (aD[6]+aD[7]));
    float u1 = (bD[0] + bD[1]) + (bD[2] + bD[3]);
    const float cS0 = bS[0] + bS[1], cD0 = bS[0] - bS[1];
    const float cS1 = bS[2] + bS[3], cD1 = bS[2] - bS[3];
    float u3 = cD0 + cD1;
    float u4 = cS0 - cS1;
    float T  = cS0 + cS1;

    const float Tp = __shfl_xor(T, 32);
    const float u2 = h ? (Tp - T) : (T - Tp);
    T += Tp;
    u0 += __shfl_xor(u0, 32);
    u1 += __shfl_xor(u1, 32);
    u3 += __shfl_xor(u3, 32);
    u4 += __shfl_xor(u4, 32);

    if (h == 0) {
      red[wv][r][0] = T;
      red[wv][r][1] = u0;
      red[wv][r][2] = u1;
      red[wv][r][3] = u2;
      red[wv][r][4] = u3;
      red[wv][r][5] = u4;
    }
  }

  asm volatile("s_waitcnt lgkmcnt(0)" ::: "memory");
  __builtin_amdgcn_s_barrier();
  asm volatile("" ::: "memory");

  // ---- tail: combine across waves (s-bits b5,b6), write 7 outs x 64 rows
  if (tid < 64) {
    const int c = tid;
    const float T0 = red[0][c][0], T1 = red[1][c][0];
    const float T2 = red[2][c][0], T3 = red[3][c][0];
    const float sT  = (T0 + T1) + (T2 + T3);
    const float inv = 1.0f / sT;            // == 1/||x||^2 (unitarity)
    const float z0 = (T0 + T1) - (T2 + T3);
    const float z1 = (T0 - T1) + (T2 - T3);
    float zr[5];
    #pragma unroll
    for (int i = 0; i < 5; ++i)
      zr[i] = (red[0][c][5-i] + red[1][c][5-i]) +
              (red[2][c][5-i] + red[3][c][5-i]);
    float* o = out + (size_t)(t0 * 64 + c) * 7;
    o[0] = z0 * inv; o[1] = z1 * inv; o[2] = zr[0] * inv; o[3] = zr[1] * inv;
    o[4] = zr[2] * inv; o[5] = zr[3] * inv; o[6] = zr[4] * inv;
  }
}

// ------------------------------- launcher ----------------------------------
extern "C" void kernel_launch(void* const* d_in, const int* in_sizes, int n_in,
                              void* d_out, int out_size, void* d_ws, size_t ws_size,
                              hipStream_t stream) {
  const float* x   = (const float*)d_in[0];
  const float* wts = (const float*)d_in[1];
  float* out = (float*)d_out;
  short* W   = (short*)d_ws;               // 2 * 128*128 bf16 = 64 KiB

  const int B     = in_sizes[0] / 128;
  const int grid  = B / 64;                // one 64-row tile per block

  qnn_build_w<<<128, 64, 0, stream>>>(wts, W);
  qnn_main<<<grid, 256, 0, stream>>>(x, W, out);
}